// Round 3
// baseline (392.542 us; speedup 1.0000x reference)
//
#include <hip/hip_runtime.h>

// MaxMin pooling: in [C, H] fp32, windows of 4 along H.
// out[c, 2i] = argmax(window) as float (strict >, first-occurrence ties)
// out[c, 2i+1] = min(window)
//
// R3: SoA-unrolled streaming shape.
//  - 4 windows/thread at wave-stride offsets: every load instruction is a
//    dense 1 KiB/wave float4 access; every store a dense 512 B/wave float2.
//  - 4 independent loads in flight per lane (MLP x4).
//  - Nontemporal stores: output has no reuse within a replay; keep L2/LLC
//    for the input stream (which the harness restore just wrote).
// Floor: 256 MiB read + 128 MiB write at ~6.3-6.6 TB/s -> ~62 us kernel.

typedef float v2f __attribute__((ext_vector_type(2)));

__device__ __forceinline__ v2f window_maxmin(float4 w)
{
    float m   = w.x;
    float idx = 0.0f;
    if (w.y > m) { m = w.y; idx = 1.0f; }
    if (w.z > m) { m = w.z; idx = 2.0f; }
    if (w.w > m) { m = w.w; idx = 3.0f; }
    float mn = fminf(fminf(w.x, w.y), fminf(w.z, w.w));
    v2f r; r.x = idx; r.y = mn;
    return r;
}

__global__ __launch_bounds__(256) void maxmin_kernel(
    const float4* __restrict__ in, float2* __restrict__ out, int nwin)
{
    int base = blockIdx.x * 1024 + (int)threadIdx.x;   // 4 windows per thread

    if (base + 768 < nwin) {
        // 4 independent dense loads
        float4 w0 = in[base];
        float4 w1 = in[base + 256];
        float4 w2 = in[base + 512];
        float4 w3 = in[base + 768];

        v2f r0 = window_maxmin(w0);
        v2f r1 = window_maxmin(w1);
        v2f r2 = window_maxmin(w2);
        v2f r3 = window_maxmin(w3);

        __builtin_nontemporal_store(r0, (v2f*)&out[base]);
        __builtin_nontemporal_store(r1, (v2f*)&out[base + 256]);
        __builtin_nontemporal_store(r2, (v2f*)&out[base + 512]);
        __builtin_nontemporal_store(r3, (v2f*)&out[base + 768]);
    } else {
        // tail (never taken for the 4096x16384 shape, kept for generality)
        for (int k = 0; k < 4; ++k) {
            int j = base + k * 256;
            if (j < nwin) {
                v2f r = window_maxmin(in[j]);
                __builtin_nontemporal_store(r, (v2f*)&out[j]);
            }
        }
    }
}

extern "C" void kernel_launch(void* const* d_in, const int* in_sizes, int n_in,
                              void* d_out, int out_size, void* d_ws, size_t ws_size,
                              hipStream_t stream)
{
    const float* in = (const float*)d_in[0];
    float* out = (float*)d_out;

    int nwin = in_sizes[0] / 4;                 // 16,777,216 windows
    int block = 256;
    int grid = (nwin + block * 4 - 1) / (block * 4);  // 16384 blocks

    maxmin_kernel<<<grid, block, 0, stream>>>(
        (const float4*)in, (float2*)out, nwin);
}